// Round 12
// baseline (136.850 us; speedup 1.0000x reference)
//
#include <hip/hip_runtime.h>
#include <hip/hip_fp16.h>

#define BATCH 8192
#define NNB 100
#define NDEV 1000000

// Merged main row space: lpo (lang*150+plat*30+os) 0..7499 | country 7500..7699
// | carrier 7700..8199 | brand 8200..10199 | plat_os 10200..10299
#define MAIN_ROWS 10300
#define MAIN_ELEMS (MAIN_ROWS * 64)   // f16 main dims, 128B rows
#define NROWS 2885
#define NP2HALF (NROWS * 64)

typedef _Float16 f16x2 __attribute__((ext_vector_type(2)));

// Static device storage (graph-capture safe).
__device__ __half  g_Pmain[MAIN_ELEMS];     // msg dims 0..63, f16, 128B rows
__device__ float   g_Ttail[MAIN_ROWS * 4];  // msg tail rows {t64,t65,t66,0} f32
__device__ float4  g_tail[NDEV];            // per-device RELU'D tail activations
__device__ __half2 g_P2dev1[NP2HALF];       // dev1 interleaved (256B rows)
__device__ float g_w0b_msg[256];    // [0:67]=W[:,0], [67:134]=b, rest 0
__device__ float g_w0b_dev1[256];
__device__ uint4 g_pack[NDEV];      // {cont_f32, lo_idx, hi_idx, 0}
// Packed f16-pair weight tables: element = {f16 W[o][k0], f16 W[o][k1]}.
__device__ unsigned g_W2_ch1[23 * 64];
__device__ unsigned g_W2_dev2[34 * 64];
__device__ unsigned g_W2_fus[48 * 64];
__device__ unsigned g_W2_c1[53 * 64];
__device__ unsigned g_W2_c2[32 * 64];
__device__ float g_bpad[5 * 64];

__device__ __forceinline__ unsigned pkh(float a, float b) {
    f16x2 v; v.x = (_Float16)a; v.y = (_Float16)b;
    return __builtin_bit_cast(unsigned, v);
}
__device__ __forceinline__ float dot2u(unsigned a, unsigned b, float c) {
#if __has_builtin(__builtin_amdgcn_fdot2)
    return __builtin_amdgcn_fdot2(__builtin_bit_cast(f16x2, a),
                                  __builtin_bit_cast(f16x2, b), c, false);
#else
    __half2 ha = *reinterpret_cast<__half2*>(&a);
    __half2 hb = *reinterpret_cast<__half2*>(&b);
    float2 fa = __half22float2(ha), fb = __half22float2(hb);
    return fmaf(fa.x, fb.x, fmaf(fa.y, fb.y, c));
#endif
}

// ---------------------------------------------------------------------------
// prep1: pack rows + f16 main table + f32 tail row table + dev1 + weights.
// Segments: NDEV | 480000 lpo | 179200 others | 41200 ttail | 184640 dev1 |
//           12160 W2 | 320 bias | 268 w0b
// ---------------------------------------------------------------------------
__global__ __launch_bounds__(256) void prep1_kernel(
    const float* __restrict__ devf,
    const float* __restrict__ lang, const float* __restrict__ plat,
    const float* __restrict__ osb, const float* __restrict__ country,
    const float* __restrict__ carrier, const float* __restrict__ brand,
    const float* __restrict__ plat_os,
    const float* __restrict__ Wmsg, const float* __restrict__ bmsg,
    const float* __restrict__ Wdev1, const float* __restrict__ bdev1,
    const float* __restrict__ Wch1, const float* __restrict__ bch1,
    const float* __restrict__ Wdev2, const float* __restrict__ bdev2,
    const float* __restrict__ Wfus, const float* __restrict__ bfus,
    const float* __restrict__ Wc1, const float* __restrict__ bc1,
    const float* __restrict__ Wc2, const float* __restrict__ bc2)
{
    long long gidx = (long long)blockIdx.x * 256 + threadIdx.x;
    if (gidx < NDEV) {
        int idx = (int)gidx;
        const float4* dr = (const float4*)(devf + (size_t)idx * 8);
        float4 a = dr[0], b4 = dr[1];
        unsigned lo = (unsigned)a.y | ((unsigned)a.z << 8)
                    | ((unsigned)a.w << 16) | ((unsigned)b4.w << 24);
        unsigned hi = (unsigned)b4.x | ((unsigned)b4.y << 9)
                    | ((unsigned)b4.z << 20);
        g_pack[idx] = make_uint4(__float_as_uint(a.x), lo, hi, 0u);
        return;
    }
    int q = (int)(gidx - NDEV);

    if (q < 480000) {                        // merged lpo main rows (f16)
        int r = q >> 6, l = q & 63;
        int lg = r / 150, rem = r - lg * 150;
        int pl = rem / 30, os_ = rem - pl * 30;
        const float* el = lang + lg * 16;
        const float* ep = plat + pl * 16;
        const float* eo = osb + os_ * 16;
        const float* Wm = Wmsg + l * 113;
        float m = 0.f;
#pragma unroll
        for (int j = 0; j < 16; j++)
            m += el[j] * Wm[1 + j] + ep[j] * Wm[17 + j] + eo[j] * Wm[33 + j];
        g_Pmain[q] = __float2half(m);
        return;
    }
    q -= 480000;
    if (q < 179200) {                        // country/carrier/brand/plat_os
        const float* tab; int C, base;
        if (q < 12800)       { tab = country; C = 49; base = 0; }
        else if (q < 44800)  { tab = carrier; C = 65; base = 12800; }
        else if (q < 172800) { tab = brand;   C = 81; base = 44800; }
        else                 { tab = plat_os; C = 97; base = 172800; }
        int q2 = q - base, r = q2 >> 6, l = q2 & 63;
        const float* e = tab + r * 16;
        const float* Wm = Wmsg + l * 113 + C;
        float m = 0.f;
#pragma unroll
        for (int j = 0; j < 16; j++) m += e[j] * Wm[j];
        g_Pmain[480000 + q] = __float2half(m);
        return;
    }
    q -= 179200;
    if (q < MAIN_ROWS * 4) {                 // f32 tail row table (d64..66)
        int row = q >> 2, d = q & 3;
        float v = 0.f;
        if (d < 3) {
            const float* Wt = Wmsg + (64 + d) * 113;
            if (row < 7500) {
                int lg = row / 150, rem = row - lg * 150;
                int pl = rem / 30, os_ = rem - pl * 30;
                const float* el = lang + lg * 16;
                const float* ep = plat + pl * 16;
                const float* eo = osb + os_ * 16;
#pragma unroll
                for (int j = 0; j < 16; j++)
                    v += el[j] * Wt[1 + j] + ep[j] * Wt[17 + j] + eo[j] * Wt[33 + j];
            } else {
                const float* tab; int C, rr;
                if (row < 7700)       { tab = country; C = 49; rr = row - 7500; }
                else if (row < 8200)  { tab = carrier; C = 65; rr = row - 7700; }
                else if (row < 10200) { tab = brand;   C = 81; rr = row - 8200; }
                else                  { tab = plat_os; C = 97; rr = row - 10200; }
                const float* e = tab + rr * 16;
#pragma unroll
                for (int j = 0; j < 16; j++) v += e[j] * Wt[C + j];
            }
        }
        g_Ttail[q] = v;
        return;
    }
    q -= MAIN_ROWS * 4;
    if (q < NP2HALF) {                       // dev1 interleaved table
        int row = q >> 6, l = q & 63, t, r;
        if (row < 50)        { t = 0; r = row; }
        else if (row < 55)   { t = 1; r = row - 50; }
        else if (row < 85)   { t = 2; r = row - 55; }
        else if (row < 285)  { t = 3; r = row - 85; }
        else if (row < 785)  { t = 4; r = row - 285; }
        else if (row < 2785) { t = 5; r = row - 785; }
        else                 { t = 6; r = row - 2785; }
        const float* tab;
        switch (t) {
            case 0: tab = lang; break;    case 1: tab = plat; break;
            case 2: tab = osb; break;     case 3: tab = country; break;
            case 4: tab = carrier; break; case 5: tab = brand; break;
            default: tab = plat_os;
        }
        const float* e = tab + r * 16;
        const float* Wm = Wdev1 + l * 113 + 1 + 16 * t;
        float m = 0.f;
#pragma unroll
        for (int j = 0; j < 16; j++) m += e[j] * Wm[j];
        float tl = 0.f;
        if (l < 3) {
            const float* Wt2 = Wdev1 + (64 + l) * 113 + 1 + 16 * t;
#pragma unroll
            for (int j = 0; j < 16; j++) tl += e[j] * Wt2[j];
        }
        g_P2dev1[q] = __halves2half2(__float2half(m), __float2half(tl));
        return;
    }
    q -= NP2HALF;
    if (q < 12160) {                         // packed f16-pair weight tables
        const float* W; int O, I, p, k0, k1, oo; unsigned* dst; int base;
        if (q < 1472) {
            base = q; W = Wch1; O = 27; I = 46; p = base >> 6;
            k0 = 2 * p; k1 = 2 * p + 1; dst = g_W2_ch1;
        } else if (q < 3648) {
            base = q - 1472; W = Wdev2; O = 50; I = 67; p = base >> 6;
            if (p < 32)      { k0 = 2 * p; k1 = 2 * p + 1; }
            else if (p == 32){ k0 = 64; k1 = 65; }
            else             { k0 = 66; k1 = -1; }
            dst = g_W2_dev2;
        } else if (q < 6720) {
            base = q - 3648; W = Wfus; O = 56; I = 94; p = base >> 6;
            if (p < 14)      { k0 = 2 * p; k1 = 2 * p + 1;
                               if (k0 >= 27) k0 = -1; if (k1 >= 27) k1 = -1; }
            else if (p < 46) { k0 = 27 + 2 * (p - 14); k1 = k0 + 1; }
            else if (p == 46){ k0 = 91; k1 = 92; }
            else             { k0 = 93; k1 = -1; }
            dst = g_W2_fus;
        } else if (q < 10112) {
            base = q - 6720; W = Wc1; O = 63; I = 106; p = base >> 6;
            if (p < 28) { k0 = 2 * p; k1 = 2 * p + 1; }
            else        { k0 = 56 + 2 * (p - 28); k1 = k0 + 1; }
            dst = g_W2_c1;
        } else {
            base = q - 10112; W = Wc2; O = 31; I = 63; p = base >> 6;
            k0 = 2 * p; k1 = 2 * p + 1; if (k1 >= 63) k1 = -1;
            dst = g_W2_c2;
        }
        oo = base & 63;
        float w0 = (oo < O && k0 >= 0 && k0 < I) ? W[oo * I + k0] : 0.f;
        float w1 = (oo < O && k1 >= 0 && k1 < I) ? W[oo * I + k1] : 0.f;
        dst[base] = pkh(w0, w1);
        return;
    }
    q -= 12160;
    if (q < 320) {
        int which = q >> 6, o = q & 63;
        const float* b; int O;
        switch (which) {
            case 0: b = bch1; O = 27; break;  case 1: b = bdev2; O = 50; break;
            case 2: b = bfus; O = 56; break;  case 3: b = bc1; O = 63; break;
            default: b = bc2; O = 31;
        }
        g_bpad[q] = (o < O) ? b[o] : 0.f;
        return;
    }
    q -= 320;
    if (q < 268) {
        int which = q / 134, k = q - which * 134;
        float* dst = which ? g_w0b_dev1 : g_w0b_msg;
        const float* W = which ? Wdev1 : Wmsg;
        const float* b = which ? bdev1 : bmsg;
        dst[k] = (k < 67) ? W[k * 113] : b[k - 67];
    }
}

// ---------------------------------------------------------------------------
// prep2: per-device RELU'D tail activations (dims 64..66), exact f32.
// ---------------------------------------------------------------------------
__global__ __launch_bounds__(256) void prep2_kernel()
{
    int idx = blockIdx.x * 256 + threadIdx.x;
    if (idx >= NDEV) return;
    uint4 r = g_pack[idx];
    float cont = __uint_as_float(r.x);
    unsigned lo = r.y, hi = r.z;
    const float4* T = (const float4*)g_Ttail;
    float4 a0 = T[(lo & 255u) * 150 + ((lo >> 8) & 255u) * 30 + ((lo >> 16) & 255u)];
    float4 a1 = T[7500 + (hi & 511u)];
    float4 a2 = T[7700 + ((hi >> 9) & 511u)];
    float4 a3 = T[8200 + (hi >> 20)];
    float4 a4 = T[10200 + (lo >> 24)];
    float s64 = a0.x + a1.x + a2.x + a3.x + a4.x;
    float s65 = a0.y + a1.y + a2.y + a3.y + a4.y;
    float s66 = a0.z + a1.z + a2.z + a3.z + a4.z;
    float t64 = fmaxf(fmaf(cont, g_w0b_msg[64], g_w0b_msg[131]) + s64, 0.f);
    float t65 = fmaxf(fmaf(cont, g_w0b_msg[65], g_w0b_msg[132]) + s65, 0.f);
    float t66 = fmaxf(fmaf(cont, g_w0b_msg[66], g_w0b_msg[133]) + s66, 0.f);
    g_tail[idx] = make_float4(t64, t65, t66, 0.f);
}

// ---------------------------------------------------------------------------
// Kernel B: one wave per edge (4 edges / 256-thread block).
// Phase 1: uniform descriptor+tail s_loads (1 group ahead); 5 ushort gathers
//   per neighbor from 128B f16 rows with SCALAR row bases; tail dims via
//   3 scalar adds of precomputed relu'd activations.
// Phase 2: packed-f16 pair GEMVs via v_dot2_f32_f16.
// ---------------------------------------------------------------------------
__global__ __launch_bounds__(256) void fused_kernel(
    const float* __restrict__ combin_feats, const float* __restrict__ chemb,
    const int* __restrict__ edges, const int* __restrict__ neibrs,
    const float* __restrict__ Wc3, const float* __restrict__ bc3,
    float* __restrict__ out)
{
    int gid = blockIdx.x * 256 + threadIdx.x;
    int e = gid >> 6;
    int lane = threadIdx.x & 63;
    int eu = __builtin_amdgcn_readfirstlane(e);

    float mw0 = g_w0b_msg[lane];        // main w0 (dims 0..63)
    float mb  = g_w0b_msg[67 + lane];   // main bias

    float acc0 = 0.f, a64 = 0.f, a65 = 0.f, a66 = 0.f;

#define MBODY(D, T)                                                           \
    {                                                                         \
        unsigned lo = (D).y, hi = (D).z;                                      \
        float cont = __uint_as_float((D).x);                                  \
        const __half* r0 = g_Pmain + (((lo & 255u) * 150u                     \
            + ((lo >> 8) & 255u) * 30u + ((lo >> 16) & 255u)) << 6);          \
        const __half* r1 = g_Pmain + ((7500u + (hi & 511u)) << 6);            \
        const __half* r2 = g_Pmain + ((7700u + ((hi >> 9) & 511u)) << 6);     \
        const __half* r3 = g_Pmain + ((8200u + (hi >> 20)) << 6);             \
        const __half* r4 = g_Pmain + ((10200u + (lo >> 24)) << 6);            \
        __half h = __hadd(__hadd(r0[lane], r1[lane]),                         \
                          __hadd(__hadd(r2[lane], r3[lane]), r4[lane]));      \
        float vm = fmaf(cont, mw0, mb) + __half2float(h);                     \
        acc0 += fmaxf(vm, 0.f);                                               \
        a64 += (T).x; a65 += (T).y; a66 += (T).z;                             \
    }

    const int4* nb4 = (const int4*)(neibrs + (size_t)eu * NNB);
    int4 nn = nb4[0];
    uint4 dc0 = g_pack[nn.x], dc1 = g_pack[nn.y];
    uint4 dc2 = g_pack[nn.z], dc3 = g_pack[nn.w];
    float4 tl0 = g_tail[nn.x], tl1 = g_tail[nn.y];
    float4 tl2 = g_tail[nn.z], tl3 = g_tail[nn.w];
#pragma unroll 1
    for (int g = 0; g < NNB / 4 - 1; ++g) {
        int4 nx = nb4[g + 1];
        uint4 pp0 = g_pack[nx.x], pp1 = g_pack[nx.y];
        uint4 pp2 = g_pack[nx.z], pp3 = g_pack[nx.w];
        float4 uu0 = g_tail[nx.x], uu1 = g_tail[nx.y];
        float4 uu2 = g_tail[nx.z], uu3 = g_tail[nx.w];
        MBODY(dc0, tl0) MBODY(dc1, tl1) MBODY(dc2, tl2) MBODY(dc3, tl3)
        dc0 = pp0; dc1 = pp1; dc2 = pp2; dc3 = pp3;
        tl0 = uu0; tl1 = uu1; tl2 = uu2; tl3 = uu3;
    }
    MBODY(dc0, tl0) MBODY(dc1, tl1) MBODY(dc2, tl2) MBODY(dc3, tl3)
#undef MBODY

    float msg_a = acc0 * 0.01f;
    // lane0->dim64, lane1->dim65, lane2->dim66 (all lanes hold all sums)
    float msg_b = ((lane == 1) ? a65 : (lane == 2) ? a66 : a64) * 0.01f;

    // ---- Phase 2 ----
    int e0 = edges[2 * eu], e1 = edges[2 * eu + 1];

    const float* crow = combin_feats + (size_t)e0 * 31;
    int chid = (int)crow[30];
    float cx = 0.f;
    if (lane < 30)      cx = crow[lane];
    else if (lane < 46) cx = chemb[(size_t)chid * 16 + (lane - 30)];

    // d1 via dev1 interleaved table (once per edge)
    float d1a, d1b;
    {
        uint4 r = g_pack[e1];
        unsigned lo = (unsigned)__builtin_amdgcn_readfirstlane((int)r.y);
        unsigned hi = (unsigned)__builtin_amdgcn_readfirstlane((int)r.z);
        float cont = __uint_as_float((unsigned)__builtin_amdgcn_readfirstlane((int)r.x));
        const __half2* q0 = g_P2dev1 + (((int)(lo & 255u)) << 6);
        const __half2* q1 = g_P2dev1 + ((50   + (int)((lo >> 8) & 255u)) << 6);
        const __half2* q2 = g_P2dev1 + ((55   + (int)((lo >> 16) & 255u)) << 6);
        const __half2* q6 = g_P2dev1 + ((2785 + (int)(lo >> 24)) << 6);
        const __half2* q3 = g_P2dev1 + ((85   + (int)(hi & 511u)) << 6);
        const __half2* q4 = g_P2dev1 + ((285  + (int)((hi >> 9) & 511u)) << 6);
        const __half2* q5 = g_P2dev1 + ((785  + (int)(hi >> 20)) << 6);
        __half2 sh = __hadd2(__hadd2(__hadd2(q0[lane], q1[lane]),
                                     __hadd2(q2[lane], q3[lane])),
                             __hadd2(__hadd2(q4[lane], q5[lane]), q6[lane]));
        float2 f = __half22float2(sh);
        float vm = fmaf(cont, g_w0b_dev1[lane], g_w0b_dev1[67 + lane]) + f.x;
        float vt = fmaf(cont, g_w0b_dev1[64 + lane], g_w0b_dev1[131 + lane]) + f.y;
        d1a = fmaxf(vm, 0.f);
        d1b = fmaxf(vt, 0.f);
    }

    // ch = relu(W_ch1 @ cx + b): 23 pairs.  (full-wave shfls)
    float cxa = __shfl(cx, (2 * lane) & 63);
    float cxb = __shfl(cx, (2 * lane + 1) & 63);
    int pk_cx = (int)pkh(cxa, cxb);
    float s = g_bpad[lane];
#pragma unroll
    for (int p = 0; p < 23; p++)
        s = dot2u((unsigned)__builtin_amdgcn_readlane(pk_cx, p),
                  g_W2_ch1[p * 64 + lane], s);
    float ch = fmaxf(s, 0.f);   // lanes >=27 exactly 0

    // d2 = relu(W_dev2 @ d1 + b): 34 pairs
    {
        float dA0 = __shfl(d1a, (2 * lane) & 63);
        float dA1 = __shfl(d1a, (2 * lane + 1) & 63);
        float dB0 = __shfl(d1b, (2 * lane) & 63);
        float dB1 = __shfl(d1b, 1);
        float a0 = (lane < 32) ? dA0 : dB0;
        float a1 = (lane < 32) ? dA1 : ((lane == 32) ? dB1 : 0.f);
        int pk_d1 = (int)pkh(a0, a1);
        s = g_bpad[64 + lane];
#pragma unroll
        for (int p = 0; p < 34; p++)
            s = dot2u((unsigned)__builtin_amdgcn_readlane(pk_d1, p),
                      g_W2_dev2[p * 64 + lane], s);
    }
    float d2 = fmaxf(s, 0.f);   // lanes >=50 exactly 0

    // fus = relu(W_fus @ [ch(27) | msg(67)] + b): 48 pairs
    {
        int j = lane - 14;
        float mA0 = __shfl(msg_a, (2 * j) & 63);
        float mA1 = __shfl(msg_a, (2 * j + 1) & 63);
        float mB0 = __shfl(msg_b, (2 * j) & 63);
        float mB1 = __shfl(msg_b, 1);
        float cv0 = __shfl(ch, (2 * lane) & 63);
        float cv1 = __shfl(ch, (2 * lane + 1) & 63);
        float m0 = (j < 32) ? mA0 : mB0;
        float m1 = (j < 32) ? mA1 : ((j == 32) ? mB1 : 0.f);
        float f0 = (lane < 14) ? cv0 : m0;
        float f1 = (lane < 14) ? cv1 : m1;
        int pk_f = (int)pkh(f0, f1);
        s = g_bpad[128 + lane];
#pragma unroll
        for (int p = 0; p < 48; p++)
            s = dot2u((unsigned)__builtin_amdgcn_readlane(pk_f, p),
                      g_W2_fus[p * 64 + lane], s);
    }
    float fus = fmaxf(s, 0.f);  // lanes >=56 exactly 0

    // h1 = relu(W_c1 @ [fus(56) | d2(50)] + b): 53 pairs
    {
        float fA0 = __shfl(fus, (2 * lane) & 63);
        float fA1 = __shfl(fus, (2 * lane + 1) & 63);
        float dD0 = __shfl(d2, (2 * (lane - 28)) & 63);
        float dD1 = __shfl(d2, (2 * (lane - 28) + 1) & 63);
        float x0 = (lane < 28) ? fA0 : dD0;
        float x1 = (lane < 28) ? fA1 : dD1;
        int pk_x = (int)pkh(x0, x1);
        s = g_bpad[192 + lane];
#pragma unroll
        for (int p = 0; p < 53; p++)
            s = dot2u((unsigned)__builtin_amdgcn_readlane(pk_x, p),
                      g_W2_c1[p * 64 + lane], s);
    }
    float h1 = fmaxf(s, 0.f);   // lane 63 exactly 0

    // h2 = relu(W_c2 @ h1 + b): 32 pairs
    {
        float y0 = __shfl(h1, (2 * lane) & 63);
        float y1 = __shfl(h1, (2 * lane + 1) & 63);
        int pk_y = (int)pkh(y0, y1);
        s = g_bpad[256 + lane];
#pragma unroll
        for (int p = 0; p < 32; p++)
            s = dot2u((unsigned)__builtin_amdgcn_readlane(pk_y, p),
                      g_W2_c2[p * 64 + lane], s);
    }
    float h2 = fmaxf(s, 0.f);

    // out = W_c3 @ h2 + b  (wave butterfly reduction, f32)
    float t = (lane < 31) ? h2 * Wc3[lane] : 0.f;
    for (int off = 32; off; off >>= 1) t += __shfl_xor(t, off);
    if (lane == 0) out[e] = t + bc3[0];
}

extern "C" void kernel_launch(void* const* d_in, const int* in_sizes, int n_in,
                              void* d_out, int out_size, void* d_ws, size_t ws_size,
                              hipStream_t stream) {
    const float* combin   = (const float*)d_in[0];
    const float* devf     = (const float*)d_in[1];
    const float* chemb    = (const float*)d_in[2];
    const float* lang     = (const float*)d_in[3];
    const float* plat     = (const float*)d_in[4];
    const float* osb      = (const float*)d_in[5];
    const float* country  = (const float*)d_in[6];
    const float* carrier  = (const float*)d_in[7];
    const float* brand    = (const float*)d_in[8];
    const float* plat_os  = (const float*)d_in[9];
    const float* Wch1 = (const float*)d_in[10]; const float* bch1 = (const float*)d_in[11];
    const float* Wmsg = (const float*)d_in[12]; const float* bmsg = (const float*)d_in[13];
    const float* Wfus = (const float*)d_in[14]; const float* bfus = (const float*)d_in[15];
    const float* Wdev1 = (const float*)d_in[16]; const float* bdev1 = (const float*)d_in[17];
    const float* Wdev2 = (const float*)d_in[18]; const float* bdev2 = (const float*)d_in[19];
    const float* Wc1 = (const float*)d_in[20]; const float* bc1 = (const float*)d_in[21];
    const float* Wc2 = (const float*)d_in[22]; const float* bc2 = (const float*)d_in[23];
    const float* Wc3 = (const float*)d_in[24]; const float* bc3 = (const float*)d_in[25];
    const int* edges  = (const int*)d_in[26];
    const int* neibrs = (const int*)d_in[27];
    float* out = (float*)d_out;

    // prep1: NDEV + 659200 + 41200 + 184640 + 12160 + 320 + 268
    long long prep_threads = (long long)NDEV + 659200 + MAIN_ROWS * 4
                           + NP2HALF + 12160 + 320 + 268;
    int prep_blocks = (int)((prep_threads + 255) / 256);
    prep1_kernel<<<prep_blocks, 256, 0, stream>>>(
        devf, lang, plat, osb, country, carrier, brand, plat_os,
        Wmsg, bmsg, Wdev1, bdev1, Wch1, bch1, Wdev2, bdev2,
        Wfus, bfus, Wc1, bc1, Wc2, bc2);

    prep2_kernel<<<(NDEV + 255) / 256, 256, 0, stream>>>();

    fused_kernel<<<BATCH / 4, 256, 0, stream>>>(
        combin, chemb, edges, neibrs, Wc3, bc3, out);
}